// Round 10
// baseline (672.422 us; speedup 1.0000x reference)
//
#include <hip/hip_runtime.h>
#include <hip/hip_bf16.h>

// Dust3R transformer block. fp32 I/O; bf16 MFMA GEMMs + bf16 MFMA flash attention.
// B=2 N=3072 C=768 H=12 HD=64.
// ws layout (liveness reuse, peak 99090432 B):
//   xnb  bf16 [6144,768]   @ 0          (live 1-2, 6-7)
//   Qb   bf16 [24,3072,64] @ 9437184    (live 3-4)
//   Kb   bf16 [24,3072,64] @ 18874368   (live 3-4)
//   x1   f32  [6144,768]   @ 9437184    (live 5-8, overlays dead Qb+Kb)
//   Vt   bf16 [24,64,3072] @ 28311552   (live 3-4)
//   obb  bf16 [6144,768]   @ 37748736   (live 4-5)
//   qkvb bf16 [6144,2304]  @ 47185920   (live 2-3)
//   hb   bf16 [6144,3072]  @ 47185920   (live 7-8, overlays dead qkvb)
//   wqkvb @ 84934656, wprojb @ 88473600, wfc1b @ 89653248, wfc2b @ 94371840

#define Nn 3072
#define Cc 768
#define Hh 12
#define Mm 6144   // B*N

typedef unsigned short ushort_t;
typedef unsigned int u32;
using s8v = __attribute__((ext_vector_type(8))) short;   // 8 bf16 (4 VGPRs)
using f4v = __attribute__((ext_vector_type(4))) float;   // MFMA acc

__device__ __forceinline__ ushort_t f2b(float x){
  u32 u = __float_as_uint(x);
  return (ushort_t)((u + 0x7fffu + ((u >> 16) & 1u)) >> 16);  // RNE
}
__device__ __forceinline__ u32 pack2(float a, float b){
  return (u32)f2b(a) | ((u32)f2b(b) << 16);
}
__device__ __forceinline__ u32 pack2t(float a, float b){   // truncation pack (cheap)
  return (__float_as_uint(a) >> 16) | (__float_as_uint(b) & 0xffff0000u);
}
__device__ __forceinline__ float b2f(ushort_t u){
  return __uint_as_float(((u32)u) << 16);
}

#define GLD16(g, l) __builtin_amdgcn_global_load_lds( \
    (const __attribute__((address_space(1))) u32*)(g), \
    (__attribute__((address_space(3))) u32*)(l), 16, 0, 0)

// ---------------- fp32 -> bf16 convert (all 4 weights, one launch) ----------------
__global__ __launch_bounds__(256) void cvt4_kernel(
    const float* __restrict__ a, ushort_t* __restrict__ oa, int na,
    const float* __restrict__ b, ushort_t* __restrict__ ob, int nb,
    const float* __restrict__ c, ushort_t* __restrict__ oc, int nc,
    const float* __restrict__ d, ushort_t* __restrict__ od)
{
  int i = (blockIdx.x*256 + threadIdx.x)*4;
  const float* src; ushort_t* dst;
  if (i < na)           { src = a + i;            dst = oa + i; }
  else if (i < na+nb)   { src = b + (i-na);       dst = ob + (i-na); }
  else if (i < na+nb+nc){ src = c + (i-na-nb);    dst = oc + (i-na-nb); }
  else                  { src = d + (i-na-nb-nc); dst = od + (i-na-nb-nc); }
  float4 v = *(const float4*)src;
  uint2 p; p.x = pack2(v.x, v.y); p.y = pack2(v.z, v.w);
  *(uint2*)dst = p;
}

// ---------------- LayerNorm (f32 in, bf16 out) ----------------
__global__ __launch_bounds__(256) void ln_kernel(const float* __restrict__ in,
    const float* __restrict__ g, const float* __restrict__ be, ushort_t* __restrict__ out)
{
  int row = blockIdx.x;
  int tid = threadIdx.x;
  size_t base = (size_t)row * Cc;
  float v[3];
  #pragma unroll
  for (int i = 0; i < 3; ++i) v[i] = in[base + tid + i*256];
  __shared__ float red[8];
  float s = v[0]+v[1]+v[2];
  #pragma unroll
  for (int off=32; off; off>>=1) s += __shfl_xor(s, off);
  int wid = tid >> 6, lane = tid & 63;
  if (lane==0) red[wid] = s;
  __syncthreads();
  float mean = (red[0]+red[1]+red[2]+red[3]) * (1.f/Cc);
  float d = 0.f;
  #pragma unroll
  for (int i=0;i<3;++i){ float t = v[i]-mean; d += t*t; }
  #pragma unroll
  for (int off=32; off; off>>=1) d += __shfl_xor(d, off);
  if (lane==0) red[4+wid] = d;
  __syncthreads();
  float var  = (red[4]+red[5]+red[6]+red[7]) * (1.f/Cc);
  float rstd = rsqrtf(var + 1e-5f);
  #pragma unroll
  for (int i=0;i<3;++i){
    int idx = tid + i*256;
    out[base+idx] = f2b((v[i]-mean)*rstd*g[idx] + be[idx]);
  }
}

// ---------------- MFMA GEMM: out[M,Nd] = A[M,K] @ W[Nd,K]^T (+epilogue) ----------------
// Tile 128 x NT (NT=128 or 64). EPI: 0 plain->bf16 | 1 +bias+resid_f32 -> f32 | 2 +bias,GELU->bf16
template<int EPI, int NT>
__global__ __launch_bounds__(256) void mgemm_kernel(
    const ushort_t* __restrict__ A, const ushort_t* __restrict__ W,
    const float* __restrict__ bias, const float* __restrict__ residf,
    void* __restrict__ outv, int Nd, int K)
{
  constexpr int JT = NT/32;           // n-subtiles per wave
  __shared__ __align__(16) ushort_t As[128*32];
  __shared__ __align__(16) ushort_t Ws[NT*32];
  int tid = threadIdx.x;
  int w = tid >> 6, lane = tid & 63;
  int g = lane >> 4, c = lane & 15;
  int wr = w >> 1, wc = w & 1;
  int m0 = blockIdx.y * 128, n0 = blockIdx.x * NT;
  int schunk = (lane & 3) * 8;
  const ushort_t* Ag = A + (size_t)(m0 + w*32 + (lane >> 2))*K + schunk;
  const ushort_t* Wg;
  if constexpr (NT == 128) Wg = W + (size_t)(n0 + w*32 + (lane >> 2))*K + schunk;
  else                     Wg = W + (size_t)(n0 + w*16 + (lane >> 2))*K + schunk;
  ushort_t* Asl = &As[w*1024];
  ushort_t* Wsl = (NT == 128) ? &Ws[w*1024] : &Ws[w*512];
  f4v acc[4][JT] = {};
  for (int k0 = 0; k0 < K; k0 += 32) {
    __syncthreads();
    GLD16(Ag + k0,        Asl);
    GLD16(Ag + 16*K + k0, Asl + 512);
    GLD16(Wg + k0,        Wsl);
    if constexpr (NT == 128) GLD16(Wg + 16*K + k0, Wsl + 512);
    __syncthreads();
    s8v af[4], wf[JT];
    #pragma unroll
    for (int i=0;i<4;++i) af[i] = *(const s8v*)&As[(wr*64 + i*16 + c)*32 + g*8];
    #pragma unroll
    for (int j=0;j<JT;++j) wf[j] = *(const s8v*)&Ws[(wc*(NT/2) + j*16 + c)*32 + g*8];
    #pragma unroll
    for (int i=0;i<4;++i)
      #pragma unroll
      for (int j=0;j<JT;++j)
        acc[i][j] = __builtin_amdgcn_mfma_f32_16x16x32_bf16(af[i], wf[j], acc[i][j], 0,0,0);
  }
  #pragma unroll
  for (int j=0;j<JT;++j){
    int col = n0 + wc*(NT/2) + j*16 + c;
    float bv = (EPI != 0) ? bias[col] : 0.f;
    #pragma unroll
    for (int i=0;i<4;++i){
      int row0 = m0 + wr*64 + i*16 + g*4;
      #pragma unroll
      for (int r=0;r<4;++r){
        float v = acc[i][j][r];
        size_t off = (size_t)(row0 + r)*Nd + col;
        if (EPI == 0) {
          ((ushort_t*)outv)[off] = f2b(v);
        } else if (EPI == 2) {
          float t = v + bv;
          ((ushort_t*)outv)[off] = f2b(0.5f*t*(1.0f + erff(t*0.70710678118654752f)));
        } else {
          ((float*)outv)[off] = v + bv + residf[off];
        }
      }
    }
  }
}

// ---------------- Repack: qkv bf16 -> RoPE'd bf16 Qb/Kb [bh][n][64], Vt [bh][64][n] ----------------
// Q pre-scaled by HD^-0.5 * log2(e) so attention can use exp2 directly.
__global__ __launch_bounds__(256) void repack_kernel(
    const ushort_t* __restrict__ qkv,
    const float* __restrict__ cx, const float* __restrict__ sx,
    const float* __restrict__ cy, const float* __restrict__ sy,
    ushort_t* __restrict__ Qb, ushort_t* __restrict__ Kb, ushort_t* __restrict__ Vt)
{
  __shared__ float Vls[64*68];
  int bh = blockIdx.y;
  int b = bh / Hh, h = bh - b*Hh;
  int n0 = blockIdx.x * 64;
  int tid = threadIdx.x;
  int tt = tid >> 2, cch = tid & 3;
  int n = n0 + tt;
  size_t rowbase = (size_t)(b*Nn + n) * 2304 + h*64;

  int half = cch >> 1, ibase = (cch & 1) * 8;
  int d1 = half*32 + ibase;
  const float* ct  = half ? cx : cy;
  const float* st_ = half ? sx : sy;
  float c1[8], s1[8], c2[8], s2[8];
  #pragma unroll
  for (int j=0;j<8;++j){
    c1[j] = ct[n*32 + ibase + j];       s1[j] = st_[n*32 + ibase + j];
    c2[j] = ct[n*32 + ibase + 16 + j];  s2[j] = st_[n*32 + ibase + 16 + j];
  }
  #pragma unroll
  for (int qk = 0; qk < 2; ++qk){
    const ushort_t* src = qkv + rowbase + qk*768;
    uint4 uv1 = *(const uint4*)(src + d1);
    uint4 uv2 = *(const uint4*)(src + d1 + 16);
    float v1[8], v2[8];
    v1[0]=b2f(uv1.x&0xffff); v1[1]=b2f(uv1.x>>16); v1[2]=b2f(uv1.y&0xffff); v1[3]=b2f(uv1.y>>16);
    v1[4]=b2f(uv1.z&0xffff); v1[5]=b2f(uv1.z>>16); v1[6]=b2f(uv1.w&0xffff); v1[7]=b2f(uv1.w>>16);
    v2[0]=b2f(uv2.x&0xffff); v2[1]=b2f(uv2.x>>16); v2[2]=b2f(uv2.y&0xffff); v2[3]=b2f(uv2.y>>16);
    v2[4]=b2f(uv2.z&0xffff); v2[5]=b2f(uv2.z>>16); v2[6]=b2f(uv2.w&0xffff); v2[7]=b2f(uv2.w>>16);
    float sc = qk ? 1.0f : 0.18033688011112042f;   // q: 0.125 * log2(e)
    float o1[8], o2[8];
    #pragma unroll
    for (int j=0;j<8;++j){
      o1[j] = (v1[j]*c1[j] - v2[j]*s1[j]) * sc;
      o2[j] = (v2[j]*c2[j] + v1[j]*s2[j]) * sc;
    }
    ushort_t* dst = (qk ? Kb : Qb) + ((size_t)bh*Nn + n)*64;
    uint4 u1, u2;
    u1.x = pack2(o1[0],o1[1]); u1.y = pack2(o1[2],o1[3]);
    u1.z = pack2(o1[4],o1[5]); u1.w = pack2(o1[6],o1[7]);
    u2.x = pack2(o2[0],o2[1]); u2.y = pack2(o2[2],o2[3]);
    u2.z = pack2(o2[4],o2[5]); u2.w = pack2(o2[6],o2[7]);
    *(uint4*)(dst + d1)      = u1;
    *(uint4*)(dst + d1 + 16) = u2;
  }

  {
    const ushort_t* src = qkv + rowbase + 1536 + cch*16;
    uint4 ua = *(const uint4*)(src);
    uint4 ub = *(const uint4*)(src + 8);
    float* lp = &Vls[tt*68 + cch*16];
    lp[0]=b2f(ua.x&0xffff); lp[1]=b2f(ua.x>>16); lp[2]=b2f(ua.y&0xffff); lp[3]=b2f(ua.y>>16);
    lp[4]=b2f(ua.z&0xffff); lp[5]=b2f(ua.z>>16); lp[6]=b2f(ua.w&0xffff); lp[7]=b2f(ua.w>>16);
    lp[8]=b2f(ub.x&0xffff); lp[9]=b2f(ub.x>>16); lp[10]=b2f(ub.y&0xffff); lp[11]=b2f(ub.y>>16);
    lp[12]=b2f(ub.z&0xffff); lp[13]=b2f(ub.z>>16); lp[14]=b2f(ub.w&0xffff); lp[15]=b2f(ub.w>>16);
  }
  __syncthreads();
  {
    int d = tid & 63, quarter = tid >> 6;
    float v[16];
    #pragma unroll
    for (int j=0;j<16;++j) v[j] = Vls[(quarter*16 + j)*68 + d];
    uint4 w0, w1;
    w0.x = pack2(v[0],v[1]);   w0.y = pack2(v[2],v[3]);
    w0.z = pack2(v[4],v[5]);   w0.w = pack2(v[6],v[7]);
    w1.x = pack2(v[8],v[9]);   w1.y = pack2(v[10],v[11]);
    w1.z = pack2(v[12],v[13]); w1.w = pack2(v[14],v[15]);
    ushort_t* dst = Vt + ((size_t)bh*64 + d)*Nn + n0 + quarter*16;
    *(uint4*)(dst)     = w0;
    *(uint4*)(dst + 8) = w1;
  }
}

// ---------------- MFMA flash attention v4: rotated software pipeline ------------------
// Same split-key + XCD-pinned structure as v3b, but the K-loop is rotated so every
// latency is covered by independent work at ZERO extra register cost:
//   1. issue K(it) loads          (wait covered by step 2's 28 MFMAs)
//   2. PV(it-1) from P in LDS + V regs loaded last iter (lgkm drain is a full phase old)
//   3. issue V(it) loads          (used next iter: ~600 cyc cover; reuses freed V regs)
//   4. QK(it)   5. exp2 + store P(it)        [Q pre-scaled by log2e -> raw v_exp_f32]
__global__ __launch_bounds__(256, 3) void fattn_kernel(
    const ushort_t* __restrict__ Qb, const ushort_t* __restrict__ Kb,
    const ushort_t* __restrict__ Vt, ushort_t* __restrict__ ob)
{
  __shared__ __align__(16) char smem[36864];  // [w][qs][16][72] bf16 P; aliases [w][64][72] Or
  __shared__ float Lred[256];
  int bh = blockIdx.x;
  int q0 = blockIdx.y * 64;
  int tid = threadIdx.x;
  int w = tid >> 6, lane = tid & 63, g = lane >> 4, c = lane & 15;

  const ushort_t* kbase = Kb + (size_t)bh*Nn*64;
  const ushort_t* vbase = Vt + (size_t)bh*64*Nn;

  s8v qf0[4], qf1[4];
  #pragma unroll
  for (int qs=0;qs<4;++qs){
    const ushort_t* qp = Qb + ((size_t)bh*Nn + q0 + qs*16 + c)*64;
    qf0[qs] = *(const s8v*)(qp + g*8);
    qf1[qs] = *(const s8v*)(qp + 32 + g*8);
  }
  s8v ones8;
  #pragma unroll
  for (int j=0;j<8;++j) ones8[j] = (short)0x3f80;   // bf16 1.0

  f4v o[4][4] = {};
  f4v l[4] = {};
  ushort_t* pw = (ushort_t*)smem + w*4608;   // wave-private 4*16*72
  s8v ka[4], kb2[4], va[4], vb[4];

  #pragma unroll
  for (int it = 0; it < 12; ++it){
    int key0 = (it*4 + w) * 64;
    // 1) K(it) loads (A-operand: A[m=key][k=dim])
    #pragma unroll
    for (int ks=0;ks<4;++ks){
      const ushort_t* kr = kbase + (size_t)(key0 + ks*16 + c)*64 + g*8;
      ka[ks]  = *(const s8v*)(kr);
      kb2[ks] = *(const s8v*)(kr + 32);
    }
    // 2) PV(it-1): P from LDS (written last iter), V regs from last iter
    if (it > 0){
      asm volatile("s_waitcnt lgkmcnt(0)" ::: "memory");
      #pragma unroll
      for (int qs=0;qs<4;++qs){
        s8v pf0 = *(const s8v*)&pw[qs*1152 + c*72 + g*8];
        s8v pf1 = *(const s8v*)&pw[qs*1152 + c*72 + 32 + g*8];
        #pragma unroll
        for (int d=0;d<4;++d){
          o[qs][d] = __builtin_amdgcn_mfma_f32_16x16x32_bf16(va[d], pf0, o[qs][d], 0,0,0);
          o[qs][d] = __builtin_amdgcn_mfma_f32_16x16x32_bf16(vb[d], pf1, o[qs][d], 0,0,0);
        }
        l[qs] = __builtin_amdgcn_mfma_f32_16x16x32_bf16(ones8, pf0, l[qs], 0,0,0);
        l[qs] = __builtin_amdgcn_mfma_f32_16x16x32_bf16(ones8, pf1, l[qs], 0,0,0);
      }
    }
    // 3) V(it) loads (A-operand: A[m=dim][k=key]); regs free after step 2
    #pragma unroll
    for (int d=0;d<4;++d){
      const ushort_t* vr = vbase + (size_t)(d*16 + c)*Nn + key0 + g*8;
      va[d] = *(const s8v*)(vr);
      vb[d] = *(const s8v*)(vr + 32);
    }
    // 4-5) S^T = K·Q^T ; p = exp2(s) -> wave-private LDS
    #pragma unroll
    for (int qs=0;qs<4;++qs){
      #pragma unroll
      for (int ks=0;ks<4;++ks){
        f4v z = {0,0,0,0};
        z = __builtin_amdgcn_mfma_f32_16x16x32_bf16(ka[ks],  qf0[qs], z, 0,0,0);
        z = __builtin_amdgcn_mfma_f32_16x16x32_bf16(kb2[ks], qf1[qs], z, 0,0,0);
        uint2 pk;
        pk.x = pack2t(__builtin_amdgcn_exp2f(z[0]), __builtin_amdgcn_exp2f(z[1]));
        pk.y = pack2t(__builtin_amdgcn_exp2f(z[2]), __builtin_amdgcn_exp2f(z[3]));
        *(uint2*)&pw[qs*1152 + c*72 + ks*16 + g*4] = pk;
      }
    }
  }
  // tail: PV(11)
  asm volatile("s_waitcnt lgkmcnt(0)" ::: "memory");
  #pragma unroll
  for (int qs=0;qs<4;++qs){
    s8v pf0 = *(const s8v*)&pw[qs*1152 + c*72 + g*8];
    s8v pf1 = *(const s8v*)&pw[qs*1152 + c*72 + 32 + g*8];
    #pragma unroll
    for (int d=0;d<4;++d){
      o[qs][d] = __builtin_amdgcn_mfma_f32_16x16x32_bf16(va[d], pf0, o[qs][d], 0,0,0);
      o[qs][d] = __builtin_amdgcn_mfma_f32_16x16x32_bf16(vb[d], pf1, o[qs][d], 0,0,0);
    }
    l[qs] = __builtin_amdgcn_mfma_f32_16x16x32_bf16(ones8, pf0, l[qs], 0,0,0);
    l[qs] = __builtin_amdgcn_mfma_f32_16x16x32_bf16(ones8, pf1, l[qs], 0,0,0);
  }

  // partials -> LDS (own slice; in-order DS makes this safe after the last P read)
  ushort_t* Or = (ushort_t*)smem;   // [w*64 + qrow][72]
  #pragma unroll
  for (int qs=0;qs<4;++qs){
    #pragma unroll
    for (int d=0;d<4;++d){
      uint2 pk;
      pk.x = pack2(o[qs][d][0], o[qs][d][1]);
      pk.y = pack2(o[qs][d][2], o[qs][d][3]);
      *(uint2*)&Or[(w*64 + qs*16 + c)*72 + d*16 + g*4] = pk;
    }
    Lred[w*64 + qs*16 + c] = l[qs][0];
  }
  __syncthreads();

  // combine: thread t owns (qrow = t>>2, dims (t&3)*16..+16)
  int qrow = tid >> 2, dseg = (tid & 3) * 16;
  float acc[16] = {};
  #pragma unroll
  for (int w2=0;w2<4;++w2){
    const ushort_t* base = &Or[(w2*64 + qrow)*72 + dseg];
    uint4 u0 = *(const uint4*)(base);
    uint4 u1 = *(const uint4*)(base + 8);
    u32 uu[8] = {u0.x,u0.y,u0.z,u0.w,u1.x,u1.y,u1.z,u1.w};
    #pragma unroll
    for (int j=0;j<8;++j){
      acc[j*2]   += b2f((ushort_t)(uu[j] & 0xffff));
      acc[j*2+1] += b2f((ushort_t)(uu[j] >> 16));
    }
  }
  float rl = 1.0f / (Lred[qrow] + Lred[64+qrow] + Lred[128+qrow] + Lred[192+qrow]);
  int b = bh / Hh, h = bh - b*Hh;
  ushort_t* op = ob + ((size_t)b*Nn + q0 + qrow)*768 + h*64 + dseg;
  uint4 w0_, w1_;
  w0_.x = pack2(acc[0]*rl, acc[1]*rl);   w0_.y = pack2(acc[2]*rl, acc[3]*rl);
  w0_.z = pack2(acc[4]*rl, acc[5]*rl);   w0_.w = pack2(acc[6]*rl, acc[7]*rl);
  w1_.x = pack2(acc[8]*rl, acc[9]*rl);   w1_.y = pack2(acc[10]*rl, acc[11]*rl);
  w1_.z = pack2(acc[12]*rl, acc[13]*rl); w1_.w = pack2(acc[14]*rl, acc[15]*rl);
  *(uint4*)(op)     = w0_;
  *(uint4*)(op + 8) = w1_;
}

extern "C" void kernel_launch(void* const* d_in, const int* in_sizes, int n_in,
                              void* d_out, int out_size, void* d_ws, size_t ws_size,
                              hipStream_t stream)
{
  const float* x      = (const float*)d_in[0];
  const float* w_qkv  = (const float*)d_in[1];
  const float* w_proj = (const float*)d_in[2];
  const float* b_proj = (const float*)d_in[3];
  const float* g1     = (const float*)d_in[4];
  const float* be1    = (const float*)d_in[5];
  const float* g2     = (const float*)d_in[6];
  const float* be2    = (const float*)d_in[7];
  const float* w_fc1  = (const float*)d_in[8];
  const float* b_fc1  = (const float*)d_in[9];
  const float* w_fc2  = (const float*)d_in[10];
  const float* b_fc2  = (const float*)d_in[11];
  const float* cx     = (const float*)d_in[12];
  const float* sx     = (const float*)d_in[13];
  const float* cy     = (const float*)d_in[14];
  const float* sy     = (const float*)d_in[15];
  float* out = (float*)d_out;

  char* ws = (char*)d_ws;
  ushort_t* xnb   = (ushort_t*)(ws);
  ushort_t* Qb    = (ushort_t*)(ws + 9437184);
  ushort_t* Kb    = (ushort_t*)(ws + 18874368);
  float*    x1    = (float*)   (ws + 9437184);    // overlays dead Qb+Kb (live 5-8)
  ushort_t* Vt    = (ushort_t*)(ws + 28311552);
  ushort_t* obb   = (ushort_t*)(ws + 37748736);
  ushort_t* qkvb  = (ushort_t*)(ws + 47185920);
  ushort_t* hb    = (ushort_t*)(ws + 47185920);   // overlays dead qkvb (live 7-8)
  ushort_t* wqkvb = (ushort_t*)(ws + 84934656);
  ushort_t* wprojb= (ushort_t*)(ws + 88473600);
  ushort_t* wfc1b = (ushort_t*)(ws + 89653248);
  ushort_t* wfc2b = (ushort_t*)(ws + 94371840);

  // 0) all weights -> bf16, one launch
  cvt4_kernel<<<(7077888/4)/256, 256, 0, stream>>>(
      w_qkv, wqkvb, 2304*768, w_proj, wprojb, 768*768,
      w_fc1, wfc1b, 3072*768, w_fc2, wfc2b);

  // 1) LN1 -> bf16
  ln_kernel<<<Mm, 256, 0, stream>>>(x, g1, be1, xnb);
  // 2) QKV = xn @ w_qkv^T -> bf16
  mgemm_kernel<0,128><<<dim3(2304/128, Mm/128), 256, 0, stream>>>(xnb, wqkvb, nullptr, nullptr, qkvb, 2304, 768);
  // 3) RoPE + repack (Qb, Kb, Vt)
  repack_kernel<<<dim3(48, 24), 256, 0, stream>>>(qkvb, cx, sx, cy, sy, Qb, Kb, Vt);
  // 4) MFMA flash attention v4 -> obb: rotated pipeline, XCD-pinned heads
  fattn_kernel<<<dim3(24, 48), 256, 0, stream>>>(Qb, Kb, Vt, obb);
  // 5) x1 = x + obb @ w_proj^T + b_proj  (f32)  — 128x64 tiles (576 blocks)
  mgemm_kernel<1,64><<<dim3(768/64, Mm/128), 256, 0, stream>>>(obb, wprojb, b_proj, x, x1, 768, 768);
  // 6) LN2 -> bf16
  ln_kernel<<<Mm, 256, 0, stream>>>(x1, g2, be2, xnb);
  // 7) h = gelu(xn @ w_fc1^T + b_fc1) -> bf16
  mgemm_kernel<2,128><<<dim3(3072/128, Mm/128), 256, 0, stream>>>(xnb, wfc1b, b_fc1, nullptr, hb, 3072, 768);
  // 8) out = x1 + h @ w_fc2^T + b_fc2  (f32) — 128x64 tiles (576 blocks)
  mgemm_kernel<1,64><<<dim3(768/64, Mm/128), 256, 0, stream>>>(hb, wfc2b, b_fc2, x1, out, 768, 3072);
}

// Round 11
// 457.985 us; speedup vs baseline: 1.4682x; 1.4682x over previous
//
#include <hip/hip_runtime.h>
#include <hip/hip_bf16.h>

// Dust3R transformer block. fp32 I/O; bf16 MFMA GEMMs + bf16 MFMA flash attention.
// B=2 N=3072 C=768 H=12 HD=64.
// ws layout (liveness reuse, peak 99090432 B):
//   xnb  bf16 [6144,768]   @ 0          (live 1-2, 6-7)
//   Qb   bf16 [24,3072,64] @ 9437184    (live 3-4)
//   Kb   bf16 [24,3072,64] @ 18874368   (live 3-4)
//   x1   f32  [6144,768]   @ 9437184    (live 5-8, overlays dead Qb+Kb)
//   Vt   bf16 [24,64,3072] @ 28311552   (live 3-4)
//   obb  bf16 [6144,768]   @ 37748736   (live 4-5)
//   qkvb bf16 [6144,2304]  @ 47185920   (live 2-3)
//   hb   bf16 [6144,3072]  @ 47185920   (live 7-8, overlays dead qkvb)
//   wqkvb @ 84934656, wprojb @ 88473600, wfc1b @ 89653248, wfc2b @ 94371840
//
// NOTE (round-9 lesson): do NOT unroll/rotate the fattn K-loop — register live-range
// growth past ~170 VGPR at launch_bounds(256,3) spills pipeline state to scratch
// (646 MB HBM writes/dispatch, 3x duration). v3b structure is the verified optimum.

#define Nn 3072
#define Cc 768
#define Hh 12
#define Mm 6144   // B*N

typedef unsigned short ushort_t;
typedef unsigned int u32;
using s8v = __attribute__((ext_vector_type(8))) short;   // 8 bf16 (4 VGPRs)
using f4v = __attribute__((ext_vector_type(4))) float;   // MFMA acc

__device__ __forceinline__ ushort_t f2b(float x){
  u32 u = __float_as_uint(x);
  return (ushort_t)((u + 0x7fffu + ((u >> 16) & 1u)) >> 16);  // RNE
}
__device__ __forceinline__ u32 pack2(float a, float b){
  return (u32)f2b(a) | ((u32)f2b(b) << 16);
}
__device__ __forceinline__ u32 pack2t(float a, float b){   // truncation pack (cheap)
  return (__float_as_uint(a) >> 16) | (__float_as_uint(b) & 0xffff0000u);
}
__device__ __forceinline__ float b2f(ushort_t u){
  return __uint_as_float(((u32)u) << 16);
}

#define GLD16(g, l) __builtin_amdgcn_global_load_lds( \
    (const __attribute__((address_space(1))) u32*)(g), \
    (__attribute__((address_space(3))) u32*)(l), 16, 0, 0)

// ---------------- fp32 -> bf16 convert (all 4 weights, one launch) ----------------
__global__ __launch_bounds__(256) void cvt4_kernel(
    const float* __restrict__ a, ushort_t* __restrict__ oa, int na,
    const float* __restrict__ b, ushort_t* __restrict__ ob, int nb,
    const float* __restrict__ c, ushort_t* __restrict__ oc, int nc,
    const float* __restrict__ d, ushort_t* __restrict__ od)
{
  int i = (blockIdx.x*256 + threadIdx.x)*4;
  const float* src; ushort_t* dst;
  if (i < na)           { src = a + i;            dst = oa + i; }
  else if (i < na+nb)   { src = b + (i-na);       dst = ob + (i-na); }
  else if (i < na+nb+nc){ src = c + (i-na-nb);    dst = oc + (i-na-nb); }
  else                  { src = d + (i-na-nb-nc); dst = od + (i-na-nb-nc); }
  float4 v = *(const float4*)src;
  uint2 p; p.x = pack2(v.x, v.y); p.y = pack2(v.z, v.w);
  *(uint2*)dst = p;
}

// ---------------- LayerNorm (f32 in, bf16 out) ----------------
__global__ __launch_bounds__(256) void ln_kernel(const float* __restrict__ in,
    const float* __restrict__ g, const float* __restrict__ be, ushort_t* __restrict__ out)
{
  int row = blockIdx.x;
  int tid = threadIdx.x;
  size_t base = (size_t)row * Cc;
  float v[3];
  #pragma unroll
  for (int i = 0; i < 3; ++i) v[i] = in[base + tid + i*256];
  __shared__ float red[8];
  float s = v[0]+v[1]+v[2];
  #pragma unroll
  for (int off=32; off; off>>=1) s += __shfl_xor(s, off);
  int wid = tid >> 6, lane = tid & 63;
  if (lane==0) red[wid] = s;
  __syncthreads();
  float mean = (red[0]+red[1]+red[2]+red[3]) * (1.f/Cc);
  float d = 0.f;
  #pragma unroll
  for (int i=0;i<3;++i){ float t = v[i]-mean; d += t*t; }
  #pragma unroll
  for (int off=32; off; off>>=1) d += __shfl_xor(d, off);
  if (lane==0) red[4+wid] = d;
  __syncthreads();
  float var  = (red[4]+red[5]+red[6]+red[7]) * (1.f/Cc);
  float rstd = rsqrtf(var + 1e-5f);
  #pragma unroll
  for (int i=0;i<3;++i){
    int idx = tid + i*256;
    out[base+idx] = f2b((v[i]-mean)*rstd*g[idx] + be[idx]);
  }
}

// ---------------- MFMA GEMM: out[M,Nd] = A[M,K] @ W[Nd,K]^T (+epilogue) ----------------
// Tile 128 x NT (NT=128 or 64). EPI: 0 plain->bf16 | 1 +bias+resid_f32 -> f32 | 2 +bias,GELU->bf16
template<int EPI, int NT>
__global__ __launch_bounds__(256) void mgemm_kernel(
    const ushort_t* __restrict__ A, const ushort_t* __restrict__ W,
    const float* __restrict__ bias, const float* __restrict__ residf,
    void* __restrict__ outv, int Nd, int K)
{
  constexpr int JT = NT/32;           // n-subtiles per wave
  __shared__ __align__(16) ushort_t As[128*32];
  __shared__ __align__(16) ushort_t Ws[NT*32];
  int tid = threadIdx.x;
  int w = tid >> 6, lane = tid & 63;
  int g = lane >> 4, c = lane & 15;
  int wr = w >> 1, wc = w & 1;
  int m0 = blockIdx.y * 128, n0 = blockIdx.x * NT;
  int schunk = (lane & 3) * 8;
  const ushort_t* Ag = A + (size_t)(m0 + w*32 + (lane >> 2))*K + schunk;
  const ushort_t* Wg;
  if constexpr (NT == 128) Wg = W + (size_t)(n0 + w*32 + (lane >> 2))*K + schunk;
  else                     Wg = W + (size_t)(n0 + w*16 + (lane >> 2))*K + schunk;
  ushort_t* Asl = &As[w*1024];
  ushort_t* Wsl = (NT == 128) ? &Ws[w*1024] : &Ws[w*512];
  f4v acc[4][JT] = {};
  for (int k0 = 0; k0 < K; k0 += 32) {
    __syncthreads();
    GLD16(Ag + k0,        Asl);
    GLD16(Ag + 16*K + k0, Asl + 512);
    GLD16(Wg + k0,        Wsl);
    if constexpr (NT == 128) GLD16(Wg + 16*K + k0, Wsl + 512);
    __syncthreads();
    s8v af[4], wf[JT];
    #pragma unroll
    for (int i=0;i<4;++i) af[i] = *(const s8v*)&As[(wr*64 + i*16 + c)*32 + g*8];
    #pragma unroll
    for (int j=0;j<JT;++j) wf[j] = *(const s8v*)&Ws[(wc*(NT/2) + j*16 + c)*32 + g*8];
    #pragma unroll
    for (int i=0;i<4;++i)
      #pragma unroll
      for (int j=0;j<JT;++j)
        acc[i][j] = __builtin_amdgcn_mfma_f32_16x16x32_bf16(af[i], wf[j], acc[i][j], 0,0,0);
  }
  #pragma unroll
  for (int j=0;j<JT;++j){
    int col = n0 + wc*(NT/2) + j*16 + c;
    float bv = (EPI != 0) ? bias[col] : 0.f;
    #pragma unroll
    for (int i=0;i<4;++i){
      int row0 = m0 + wr*64 + i*16 + g*4;
      #pragma unroll
      for (int r=0;r<4;++r){
        float v = acc[i][j][r];
        size_t off = (size_t)(row0 + r)*Nd + col;
        if (EPI == 0) {
          ((ushort_t*)outv)[off] = f2b(v);
        } else if (EPI == 2) {
          float t = v + bv;
          ((ushort_t*)outv)[off] = f2b(0.5f*t*(1.0f + erff(t*0.70710678118654752f)));
        } else {
          ((float*)outv)[off] = v + bv + residf[off];
        }
      }
    }
  }
}

// ---------------- Repack: qkv bf16 -> RoPE'd bf16 Qb/Kb [bh][n][64], Vt [bh][64][n] ----------------
// Q pre-scaled by HD^-0.5 * log2(e) so attention can use exp2 directly.
__global__ __launch_bounds__(256) void repack_kernel(
    const ushort_t* __restrict__ qkv,
    const float* __restrict__ cx, const float* __restrict__ sx,
    const float* __restrict__ cy, const float* __restrict__ sy,
    ushort_t* __restrict__ Qb, ushort_t* __restrict__ Kb, ushort_t* __restrict__ Vt)
{
  __shared__ float Vls[64*68];
  int bh = blockIdx.y;
  int b = bh / Hh, h = bh - b*Hh;
  int n0 = blockIdx.x * 64;
  int tid = threadIdx.x;
  int tt = tid >> 2, cch = tid & 3;
  int n = n0 + tt;
  size_t rowbase = (size_t)(b*Nn + n) * 2304 + h*64;

  int half = cch >> 1, ibase = (cch & 1) * 8;
  int d1 = half*32 + ibase;
  const float* ct  = half ? cx : cy;
  const float* st_ = half ? sx : sy;
  float c1[8], s1[8], c2[8], s2[8];
  #pragma unroll
  for (int j=0;j<8;++j){
    c1[j] = ct[n*32 + ibase + j];       s1[j] = st_[n*32 + ibase + j];
    c2[j] = ct[n*32 + ibase + 16 + j];  s2[j] = st_[n*32 + ibase + 16 + j];
  }
  #pragma unroll
  for (int qk = 0; qk < 2; ++qk){
    const ushort_t* src = qkv + rowbase + qk*768;
    uint4 uv1 = *(const uint4*)(src + d1);
    uint4 uv2 = *(const uint4*)(src + d1 + 16);
    float v1[8], v2[8];
    v1[0]=b2f(uv1.x&0xffff); v1[1]=b2f(uv1.x>>16); v1[2]=b2f(uv1.y&0xffff); v1[3]=b2f(uv1.y>>16);
    v1[4]=b2f(uv1.z&0xffff); v1[5]=b2f(uv1.z>>16); v1[6]=b2f(uv1.w&0xffff); v1[7]=b2f(uv1.w>>16);
    v2[0]=b2f(uv2.x&0xffff); v2[1]=b2f(uv2.x>>16); v2[2]=b2f(uv2.y&0xffff); v2[3]=b2f(uv2.y>>16);
    v2[4]=b2f(uv2.z&0xffff); v2[5]=b2f(uv2.z>>16); v2[6]=b2f(uv2.w&0xffff); v2[7]=b2f(uv2.w>>16);
    float sc = qk ? 1.0f : 0.18033688011112042f;   // q: 0.125 * log2(e)
    float o1[8], o2[8];
    #pragma unroll
    for (int j=0;j<8;++j){
      o1[j] = (v1[j]*c1[j] - v2[j]*s1[j]) * sc;
      o2[j] = (v2[j]*c2[j] + v1[j]*s2[j]) * sc;
    }
    ushort_t* dst = (qk ? Kb : Qb) + ((size_t)bh*Nn + n)*64;
    uint4 u1, u2;
    u1.x = pack2(o1[0],o1[1]); u1.y = pack2(o1[2],o1[3]);
    u1.z = pack2(o1[4],o1[5]); u1.w = pack2(o1[6],o1[7]);
    u2.x = pack2(o2[0],o2[1]); u2.y = pack2(o2[2],o2[3]);
    u2.z = pack2(o2[4],o2[5]); u2.w = pack2(o2[6],o2[7]);
    *(uint4*)(dst + d1)      = u1;
    *(uint4*)(dst + d1 + 16) = u2;
  }

  {
    const ushort_t* src = qkv + rowbase + 1536 + cch*16;
    uint4 ua = *(const uint4*)(src);
    uint4 ub = *(const uint4*)(src + 8);
    float* lp = &Vls[tt*68 + cch*16];
    lp[0]=b2f(ua.x&0xffff); lp[1]=b2f(ua.x>>16); lp[2]=b2f(ua.y&0xffff); lp[3]=b2f(ua.y>>16);
    lp[4]=b2f(ua.z&0xffff); lp[5]=b2f(ua.z>>16); lp[6]=b2f(ua.w&0xffff); lp[7]=b2f(ua.w>>16);
    lp[8]=b2f(ub.x&0xffff); lp[9]=b2f(ub.x>>16); lp[10]=b2f(ub.y&0xffff); lp[11]=b2f(ub.y>>16);
    lp[12]=b2f(ub.z&0xffff); lp[13]=b2f(ub.z>>16); lp[14]=b2f(ub.w&0xffff); lp[15]=b2f(ub.w>>16);
  }
  __syncthreads();
  {
    int d = tid & 63, quarter = tid >> 6;
    float v[16];
    #pragma unroll
    for (int j=0;j<16;++j) v[j] = Vls[(quarter*16 + j)*68 + d];
    uint4 w0, w1;
    w0.x = pack2(v[0],v[1]);   w0.y = pack2(v[2],v[3]);
    w0.z = pack2(v[4],v[5]);   w0.w = pack2(v[6],v[7]);
    w1.x = pack2(v[8],v[9]);   w1.y = pack2(v[10],v[11]);
    w1.z = pack2(v[12],v[13]); w1.w = pack2(v[14],v[15]);
    ushort_t* dst = Vt + ((size_t)bh*64 + d)*Nn + n0 + quarter*16;
    *(uint4*)(dst)     = w0;
    *(uint4*)(dst + 8) = w1;
  }
}

// ---------------- MFMA flash attention v3b (verified 128.5 us) + exp2 fold ------------
// split-key waves, XCD-pinned heads: grid (x=bh=24, y=qtile=48) -> xcd = bh%8,
// KV working set 2.3 MB < 4 MB L2/XCD. K/V direct global->VGPR loads (L2 hits).
// Plain rolled K-loop — see round-9 note above.
__global__ __launch_bounds__(256, 3) void fattn_kernel(
    const ushort_t* __restrict__ Qb, const ushort_t* __restrict__ Kb,
    const ushort_t* __restrict__ Vt, ushort_t* __restrict__ ob)
{
  __shared__ __align__(16) char smem[36864];  // [w][qs][16][72] bf16 P; aliases [w][64][72] Or
  __shared__ float Lred[256];
  int bh = blockIdx.x;
  int q0 = blockIdx.y * 64;
  int tid = threadIdx.x;
  int w = tid >> 6, lane = tid & 63, g = lane >> 4, c = lane & 15;

  const ushort_t* kbase = Kb + (size_t)bh*Nn*64;
  const ushort_t* vbase = Vt + (size_t)bh*64*Nn;

  s8v qf0[4], qf1[4];
  #pragma unroll
  for (int qs=0;qs<4;++qs){
    const ushort_t* qp = Qb + ((size_t)bh*Nn + q0 + qs*16 + c)*64;
    qf0[qs] = *(const s8v*)(qp + g*8);
    qf1[qs] = *(const s8v*)(qp + 32 + g*8);
  }
  s8v ones8;
  #pragma unroll
  for (int j=0;j<8;++j) ones8[j] = (short)0x3f80;   // bf16 1.0

  f4v o[4][4] = {};
  f4v l[4] = {};
  ushort_t* pw = (ushort_t*)smem + w*4608;   // wave-private 4*16*72

  for (int it = 0; it < 12; ++it){
    int key0 = (it*4 + w) * 64;
    // K fragments direct from global (A-operand: A[m=key][k=dim])
    s8v ka[4], kb2[4];
    #pragma unroll
    for (int ks=0;ks<4;++ks){
      const ushort_t* kr = kbase + (size_t)(key0 + ks*16 + c)*64 + g*8;
      ka[ks]  = *(const s8v*)(kr);
      kb2[ks] = *(const s8v*)(kr + 32);
    }
    // S^T = K·Q^T per q-subtile; p = exp2(s) -> wave-private LDS
    #pragma unroll
    for (int qs=0;qs<4;++qs){
      #pragma unroll
      for (int ks=0;ks<4;++ks){
        f4v z = {0,0,0,0};
        z = __builtin_amdgcn_mfma_f32_16x16x32_bf16(ka[ks],  qf0[qs], z, 0,0,0);
        z = __builtin_amdgcn_mfma_f32_16x16x32_bf16(kb2[ks], qf1[qs], z, 0,0,0);
        uint2 pk;
        pk.x = pack2t(__builtin_amdgcn_exp2f(z[0]), __builtin_amdgcn_exp2f(z[1]));
        pk.y = pack2t(__builtin_amdgcn_exp2f(z[2]), __builtin_amdgcn_exp2f(z[3]));
        *(uint2*)&pw[qs*1152 + c*72 + ks*16 + g*4] = pk;
      }
    }
    asm volatile("s_waitcnt lgkmcnt(0)" ::: "memory");
    // V^T fragments direct from global (A-operand: A[m=dim][k=key])
    s8v va[4], vb[4];
    #pragma unroll
    for (int d=0;d<4;++d){
      const ushort_t* vr = vbase + (size_t)(d*16 + c)*Nn + key0 + g*8;
      va[d] = *(const s8v*)(vr);
      vb[d] = *(const s8v*)(vr + 32);
    }
    #pragma unroll
    for (int qs=0;qs<4;++qs){
      s8v pf0 = *(const s8v*)&pw[qs*1152 + c*72 + g*8];
      s8v pf1 = *(const s8v*)&pw[qs*1152 + c*72 + 32 + g*8];
      #pragma unroll
      for (int d=0;d<4;++d){
        o[qs][d] = __builtin_amdgcn_mfma_f32_16x16x32_bf16(va[d], pf0, o[qs][d], 0,0,0);
        o[qs][d] = __builtin_amdgcn_mfma_f32_16x16x32_bf16(vb[d], pf1, o[qs][d], 0,0,0);
      }
      l[qs] = __builtin_amdgcn_mfma_f32_16x16x32_bf16(ones8, pf0, l[qs], 0,0,0);
      l[qs] = __builtin_amdgcn_mfma_f32_16x16x32_bf16(ones8, pf1, l[qs], 0,0,0);
    }
  }

  // partials -> LDS (own slice; in-order DS makes this safe after the last P read)
  ushort_t* Or = (ushort_t*)smem;   // [w*64 + qrow][72]
  #pragma unroll
  for (int qs=0;qs<4;++qs){
    #pragma unroll
    for (int d=0;d<4;++d){
      uint2 pk;
      pk.x = pack2(o[qs][d][0], o[qs][d][1]);
      pk.y = pack2(o[qs][d][2], o[qs][d][3]);
      *(uint2*)&Or[(w*64 + qs*16 + c)*72 + d*16 + g*4] = pk;
    }
    Lred[w*64 + qs*16 + c] = l[qs][0];
  }
  __syncthreads();

  // combine: thread t owns (qrow = t>>2, dims (t&3)*16..+16)
  int qrow = tid >> 2, dseg = (tid & 3) * 16;
  float acc[16] = {};
  #pragma unroll
  for (int w2=0;w2<4;++w2){
    const ushort_t* base = &Or[(w2*64 + qrow)*72 + dseg];
    uint4 u0 = *(const uint4*)(base);
    uint4 u1 = *(const uint4*)(base + 8);
    u32 uu[8] = {u0.x,u0.y,u0.z,u0.w,u1.x,u1.y,u1.z,u1.w};
    #pragma unroll
    for (int j=0;j<8;++j){
      acc[j*2]   += b2f((ushort_t)(uu[j] & 0xffff));
      acc[j*2+1] += b2f((ushort_t)(uu[j] >> 16));
    }
  }
  float rl = 1.0f / (Lred[qrow] + Lred[64+qrow] + Lred[128+qrow] + Lred[192+qrow]);
  int b = bh / Hh, h = bh - b*Hh;
  ushort_t* op = ob + ((size_t)b*Nn + q0 + qrow)*768 + h*64 + dseg;
  uint4 w0_, w1_;
  w0_.x = pack2(acc[0]*rl, acc[1]*rl);   w0_.y = pack2(acc[2]*rl, acc[3]*rl);
  w0_.z = pack2(acc[4]*rl, acc[5]*rl);   w0_.w = pack2(acc[6]*rl, acc[7]*rl);
  w1_.x = pack2(acc[8]*rl, acc[9]*rl);   w1_.y = pack2(acc[10]*rl, acc[11]*rl);
  w1_.z = pack2(acc[12]*rl, acc[13]*rl); w1_.w = pack2(acc[14]*rl, acc[15]*rl);
  *(uint4*)(op)     = w0_;
  *(uint4*)(op + 8) = w1_;
}

extern "C" void kernel_launch(void* const* d_in, const int* in_sizes, int n_in,
                              void* d_out, int out_size, void* d_ws, size_t ws_size,
                              hipStream_t stream)
{
  const float* x      = (const float*)d_in[0];
  const float* w_qkv  = (const float*)d_in[1];
  const float* w_proj = (const float*)d_in[2];
  const float* b_proj = (const float*)d_in[3];
  const float* g1     = (const float*)d_in[4];
  const float* be1    = (const float*)d_in[5];
  const float* g2     = (const float*)d_in[6];
  const float* be2    = (const float*)d_in[7];
  const float* w_fc1  = (const float*)d_in[8];
  const float* b_fc1  = (const float*)d_in[9];
  const float* w_fc2  = (const float*)d_in[10];
  const float* b_fc2  = (const float*)d_in[11];
  const float* cx     = (const float*)d_in[12];
  const float* sx     = (const float*)d_in[13];
  const float* cy     = (const float*)d_in[14];
  const float* sy     = (const float*)d_in[15];
  float* out = (float*)d_out;

  char* ws = (char*)d_ws;
  ushort_t* xnb   = (ushort_t*)(ws);
  ushort_t* Qb    = (ushort_t*)(ws + 9437184);
  ushort_t* Kb    = (ushort_t*)(ws + 18874368);
  float*    x1    = (float*)   (ws + 9437184);    // overlays dead Qb+Kb (live 5-8)
  ushort_t* Vt    = (ushort_t*)(ws + 28311552);
  ushort_t* obb   = (ushort_t*)(ws + 37748736);
  ushort_t* qkvb  = (ushort_t*)(ws + 47185920);
  ushort_t* hb    = (ushort_t*)(ws + 47185920);   // overlays dead qkvb (live 7-8)
  ushort_t* wqkvb = (ushort_t*)(ws + 84934656);
  ushort_t* wprojb= (ushort_t*)(ws + 88473600);
  ushort_t* wfc1b = (ushort_t*)(ws + 89653248);
  ushort_t* wfc2b = (ushort_t*)(ws + 94371840);

  // 0) all weights -> bf16, one launch
  cvt4_kernel<<<(7077888/4)/256, 256, 0, stream>>>(
      w_qkv, wqkvb, 2304*768, w_proj, wprojb, 768*768,
      w_fc1, wfc1b, 3072*768, w_fc2, wfc2b);

  // 1) LN1 -> bf16
  ln_kernel<<<Mm, 256, 0, stream>>>(x, g1, be1, xnb);
  // 2) QKV = xn @ w_qkv^T -> bf16
  mgemm_kernel<0,128><<<dim3(2304/128, Mm/128), 256, 0, stream>>>(xnb, wqkvb, nullptr, nullptr, qkvb, 2304, 768);
  // 3) RoPE + repack (Qb, Kb, Vt)
  repack_kernel<<<dim3(48, 24), 256, 0, stream>>>(qkvb, cx, sx, cy, sy, Qb, Kb, Vt);
  // 4) MFMA flash attention v3b -> obb: XCD-pinned heads, exp2 softmax
  fattn_kernel<<<dim3(24, 48), 256, 0, stream>>>(Qb, Kb, Vt, obb);
  // 5) x1 = x + obb @ w_proj^T + b_proj  (f32)  — 128x64 tiles (576 blocks)
  mgemm_kernel<1,64><<<dim3(768/64, Mm/128), 256, 0, stream>>>(obb, wprojb, b_proj, x, x1, 768, 768);
  // 6) LN2 -> bf16
  ln_kernel<<<Mm, 256, 0, stream>>>(x1, g2, be2, xnb);
  // 7) h = gelu(xn @ w_fc1^T + b_fc1) -> bf16
  mgemm_kernel<2,128><<<dim3(3072/128, Mm/128), 256, 0, stream>>>(xnb, wfc1b, b_fc1, nullptr, hb, 3072, 768);
  // 8) out = x1 + h @ w_fc2^T + b_fc2  (f32) — 128x64 tiles (576 blocks)
  mgemm_kernel<1,64><<<dim3(768/64, Mm/128), 256, 0, stream>>>(hb, wfc2b, b_fc2, x1, out, 768, 3072);
}